// Round 1
// baseline (853.877 us; speedup 1.0000x reference)
//
#include <hip/hip_runtime.h>
#include <stdint.h>

// Problem constants
constexpr int B_ = 8, N_ = 4096, E_ = 2048, C_ = 128;
constexpr int CN = 144;   // padded column dim: 128 channels + 1 ones-col + 15 pad
constexpr int KT = 32;    // K tile (bf16 16x16x32 MFMA)

typedef short bf16x8 __attribute__((ext_vector_type(8)));
typedef float f32x4  __attribute__((ext_vector_type(4)));

__device__ inline uint16_t bf16_rne(float f) {
    uint32_t u = __builtin_bit_cast(uint32_t, f);
    return (uint16_t)((u + 0x7FFFu + ((u >> 16) & 1u)) >> 16);
}
__device__ inline uint16_t bf16_trunc(float f) {   // exact for 0.0 / 1.0 (H entries)
    return (uint16_t)(__builtin_bit_cast(uint32_t, f) >> 16);
}

// ---------------------------------------------------------------------------
// prep: W^T -> bf16 [CN][128]; fill constant rows 128..143 of xwbT and ebfT
// (row 128 = 1.0 -> ones-column producing s_e / d_n in the GEMMs)
// ---------------------------------------------------------------------------
__global__ void prep_kernel(const float* __restrict__ W,
                            uint16_t* __restrict__ WTb,
                            uint16_t* __restrict__ xwbT,
                            uint16_t* __restrict__ ebfT) {
    const int NW = CN * C_;            // 18432
    const int NX = B_ * 16 * N_;       // 524288
    const int NE = B_ * 16 * E_;       // 262144
    int stride = gridDim.x * blockDim.x;
    for (int i = blockIdx.x * blockDim.x + threadIdx.x; i < NW + NX + NE; i += stride) {
        if (i < NW) {
            int c = i >> 7, k = i & 127;
            float v = (c < C_) ? W[k * C_ + c] : 0.f;
            WTb[i] = bf16_rne(v);
        } else if (i < NW + NX) {
            int j = i - NW;
            int b = j / (16 * N_);
            int rr = j - b * (16 * N_);
            int r = rr >> 12, n = rr & (N_ - 1);
            xwbT[(size_t)b * CN * N_ + (size_t)(C_ + r) * N_ + n] = (r == 0) ? 0x3F80 : 0;
        } else {
            int j = i - NW - NX;
            int b = j / (16 * E_);
            int rr = j - b * (16 * E_);
            int r = rr >> 11, n = rr & (E_ - 1);
            ebfT[(size_t)b * CN * E_ + (size_t)(C_ + r) * E_ + n] = (r == 0) ? 0x3F80 : 0;
        }
    }
}

// ---------------------------------------------------------------------------
// Unified MFMA GEMM, C[m, 0..143] = A[m,:] @ B[:,0..143]
//  MODE 0 (fc) : A = x   [N_ x 128] row-major (NT), B = W^T bf16, out = xwbT (bf16, C^T, +bias)
//  MODE 1 (v2e): A = H^T [E_ x N_ ] (T: addr k*E_+m), B = xwbT,   out = ebfT (bf16, C^T, /s_e)
//  MODE 2 (e2v): A = H   [N_ x E_ ] row-major (NT),  B = ebfT,    out = v fp32 row-major, /d_n
// Block: 128 threads = 2 waves, M-tile 32 (16 rows/wave), full 144 cols (9 MFMA tiles).
// Col 128 of the accumulator is s_e / d_n via the ones-column.
// ---------------------------------------------------------------------------
template <int MODE>
__global__ __launch_bounds__(128)
void gemm_k(const float* __restrict__ Ab, const uint16_t* __restrict__ Btb,
            const float* __restrict__ bias, uint16_t* __restrict__ outT,
            float* __restrict__ outF) {
    constexpr bool ATR = (MODE == 1);
    constexpr int  K   = (MODE == 0) ? C_ : (MODE == 1) ? N_ : E_;
    constexpr int  M   = (MODE == 1) ? E_ : N_;
    constexpr int  LDA = (MODE == 0) ? C_ : E_;                 // T: k*LDA+m ; NT: m*LDA+k
    constexpr size_t ABS = (MODE == 0) ? (size_t)N_ * C_ : (size_t)N_ * E_;
    constexpr int  LDB = K;                                     // Bt rows are length-K
    constexpr size_t BBS = (MODE == 0) ? 0 : (size_t)CN * K;
    constexpr int  OLD = M;
    constexpr size_t OBS = (size_t)CN * M;
    constexpr int  KS  = K / KT;
    constexpr int  NSEG = CN * KT / 8;                          // 576 16B segments of B tile

    __shared__ uint16_t Alds[32 * KT];    // [m][k], stride 32
    __shared__ uint16_t Blds[CN * KT];    // [c][k], stride 32

    const int t     = threadIdx.x;
    const int batch = blockIdx.x & 7;     // consecutive blocks -> different XCDs -> per-XCD B locality
    const int m0    = (blockIdx.x >> 3) * 32;
    const int lane  = t & 63, wave = t >> 6;
    const int l15   = lane & 15, quad = lane >> 4;

    const float*    Ap = Ab + (size_t)batch * ABS;
    const uint16_t* Bp = Btb + (size_t)batch * BBS;

    f32x4 acc[9];
#pragma unroll
    for (int j = 0; j < 9; ++j) acc[j] = (f32x4){0.f, 0.f, 0.f, 0.f};

    int am, ak;
    if (ATR) { am = t & 31;  ak = (t >> 5) * 8; }
    else     { am = t >> 2;  ak = (t & 3) * 8;  }

    for (int s = 0; s < KS; ++s) {
        const int k0 = s * KT;
        // ---- global loads (issue early; fly during previous MFMAs) ----
        float av[8];
        if (ATR) {
            const float* ap = Ap + (size_t)(k0 + ak) * LDA + (m0 + am);
#pragma unroll
            for (int i = 0; i < 8; ++i) av[i] = ap[(size_t)i * LDA];
        } else {
            const float* ap = Ap + (size_t)(m0 + am) * LDA + (k0 + ak);
            const float4 f0 = *(const float4*)ap;
            const float4 f1 = *(const float4*)(ap + 4);
            av[0] = f0.x; av[1] = f0.y; av[2] = f0.z; av[3] = f0.w;
            av[4] = f1.x; av[5] = f1.y; av[6] = f1.z; av[7] = f1.w;
        }
        uint4 bv[5];
#pragma unroll
        for (int j = 0; j < 5; ++j) {
            int seg = t + 128 * j;
            if (seg < NSEG) {
                int c = seg >> 2, kk = (seg & 3) * 8;
                bv[j] = *(const uint4*)(Bp + (size_t)c * LDB + k0 + kk);
            }
        }
        __syncthreads();   // previous iteration's fragment reads complete
        // ---- LDS stores ----
        uint32_t p0, p1, p2, p3;
        if (MODE == 0) {   // x needs round-to-nearest
            p0 = (uint32_t)bf16_rne(av[0]) | ((uint32_t)bf16_rne(av[1]) << 16);
            p1 = (uint32_t)bf16_rne(av[2]) | ((uint32_t)bf16_rne(av[3]) << 16);
            p2 = (uint32_t)bf16_rne(av[4]) | ((uint32_t)bf16_rne(av[5]) << 16);
            p3 = (uint32_t)bf16_rne(av[6]) | ((uint32_t)bf16_rne(av[7]) << 16);
        } else {           // H is 0/1: truncation exact
            p0 = (uint32_t)bf16_trunc(av[0]) | ((uint32_t)bf16_trunc(av[1]) << 16);
            p1 = (uint32_t)bf16_trunc(av[2]) | ((uint32_t)bf16_trunc(av[3]) << 16);
            p2 = (uint32_t)bf16_trunc(av[4]) | ((uint32_t)bf16_trunc(av[5]) << 16);
            p3 = (uint32_t)bf16_trunc(av[6]) | ((uint32_t)bf16_trunc(av[7]) << 16);
        }
        *(uint4*)&Alds[am * KT + ak] = make_uint4(p0, p1, p2, p3);
#pragma unroll
        for (int j = 0; j < 5; ++j) {
            int seg = t + 128 * j;
            if (seg < NSEG) *(uint4*)&Blds[seg * 8] = bv[j];
        }
        __syncthreads();
        // ---- fragments + MFMA ----
        bf16x8 af = *(const bf16x8*)&Alds[(wave * 16 + l15) * KT + quad * 8];
#pragma unroll
        for (int j = 0; j < 9; ++j) {
            bf16x8 bf = *(const bf16x8*)&Blds[(j * 16 + l15) * KT + quad * 8];
            acc[j] = __builtin_amdgcn_mfma_f32_16x16x32_bf16(af, bf, acc[j], 0, 0, 0);
        }
    }

    // ---- epilogue ----
    const int row = m0 + wave * 16 + quad * 4;
    float mul[4] = {1.f, 1.f, 1.f, 1.f};
    if constexpr (MODE != 0) {
        __shared__ float s_sh[32];
        if (l15 == 0) {
#pragma unroll
            for (int r = 0; r < 4; ++r) s_sh[wave * 16 + quad * 4 + r] = acc[8][r];
        }
        __syncthreads();
#pragma unroll
        for (int r = 0; r < 4; ++r) {
            float sv = s_sh[wave * 16 + quad * 4 + r];
            mul[r] = (sv > 0.f) ? 1.f / sv : 0.f;
        }
    }

    if constexpr (MODE == 2) {
        float* op = outF + (size_t)batch * ((size_t)N_ * C_) + (size_t)row * C_;
#pragma unroll
        for (int j = 0; j < 8; ++j) {
            int c = j * 16 + l15;
#pragma unroll
            for (int r = 0; r < 4; ++r) op[(size_t)r * C_ + c] = acc[j][r] * mul[r];
        }
    } else {
#pragma unroll
        for (int j = 0; j < 8; ++j) {
            int c = j * 16 + l15;
            float add = 0.f;
            if (MODE == 0) add = bias[c];
            float v0, v1, v2, v3;
            if (MODE == 0) {
                v0 = acc[j][0] + add; v1 = acc[j][1] + add;
                v2 = acc[j][2] + add; v3 = acc[j][3] + add;
            } else {
                v0 = acc[j][0] * mul[0]; v1 = acc[j][1] * mul[1];
                v2 = acc[j][2] * mul[2]; v3 = acc[j][3] * mul[3];
            }
            uint32_t q0 = (uint32_t)bf16_rne(v0) | ((uint32_t)bf16_rne(v1) << 16);
            uint32_t q1 = (uint32_t)bf16_rne(v2) | ((uint32_t)bf16_rne(v3) << 16);
            uint16_t* op = outT + (size_t)batch * OBS + (size_t)c * OLD + row;
            *(uint2*)op = make_uint2(q0, q1);   // 4 consecutive rows (C^T layout)
        }
    }
}

// ---------------------------------------------------------------------------
extern "C" void kernel_launch(void* const* d_in, const int* in_sizes, int n_in,
                              void* d_out, int out_size, void* d_ws, size_t ws_size,
                              hipStream_t stream) {
    const float* x    = (const float*)d_in[0];   // [8,4096,128]
    const float* H    = (const float*)d_in[1];   // [8,4096,2048]
    const float* W    = (const float*)d_in[2];   // [128,128]
    const float* bias = (const float*)d_in[3];   // [128]
    float* out = (float*)d_out;                  // [8,4096,128]

    // Scratch: WTb + ebfT in d_ws (~4.8 MB); xwbT (9.4 MB) lives in d_out,
    // which is dead scratch until e2v overwrites every element of it.
    uint16_t* WTb  = (uint16_t*)d_ws;                          // CN*128
    uint16_t* ebfT = WTb + (size_t)CN * C_;                    // [8][CN][E_]
    uint16_t* xwbT = (uint16_t*)d_out;                         // [8][CN][N_]

    prep_kernel<<<dim3(512), dim3(256), 0, stream>>>(W, WTb, xwbT, ebfT);
    gemm_k<0><<<dim3(8 * (N_ / 32)), dim3(128), 0, stream>>>(x, WTb, bias, xwbT, nullptr);
    gemm_k<1><<<dim3(8 * (E_ / 32)), dim3(128), 0, stream>>>(H, xwbT, nullptr, ebfT, nullptr);
    gemm_k<2><<<dim3(8 * (N_ / 32)), dim3(128), 0, stream>>>(H, ebfT, nullptr, nullptr, out);
}